// Round 17
// baseline (171.810 us; speedup 1.0000x reference)
//
#include <hip/hip_runtime.h>
#include <cmath>

#define TT    2048
#define CC    768
#define NHEAD 12
#define LWIN  256
#define BBATCH 2
#define MROWS 4096   // B*T
#define QBA   128    // query rows per q-tile (4 waves x 32)
#define KB    64     // keys per tile
#define NSLOT 72     // stream-2 chunks of 4 tiles
#define L2E   1.4426950408889634f
#define QS    (0.125f * L2E)   // folded into Q at GEMM epilogue

typedef unsigned int u32;
typedef u32 u32x2 __attribute__((ext_vector_type(2)));
typedef u32 u32x4 __attribute__((ext_vector_type(4)));
typedef short bf16x8 __attribute__((ext_vector_type(8)));
typedef float f32x16 __attribute__((ext_vector_type(16)));

union F4 { u32x4 u; bf16x8 h; };

__device__ __forceinline__ unsigned short b16(float a) {
  u32 u = __float_as_uint(a);
  return (unsigned short)((u + 0x7FFFu + ((u >> 16) & 1u)) >> 16);
}
__device__ __forceinline__ u32 pk2(float a, float b) {
  return (u32)b16(a) | ((u32)b16(b) << 16);
}

// ---------------------------------------------------------------- fused prep
// blocks [0,1536): x -> bf16. [1536,3264): w_attn^T -> wtm rows 0..2303.
// [3264,3840): w_proj^T -> wtp. [3840,3984): w_sel1^T -> wtm rows 2304..2495.
__global__ __launch_bounds__(256) void prep_kernel(
    const float* __restrict__ x, unsigned short* __restrict__ xb,
    const float* __restrict__ w_attn, unsigned short* __restrict__ wtm,
    const float* __restrict__ w_proj, unsigned short* __restrict__ wtp,
    const float* __restrict__ w_sel1) {
  __shared__ float t[32][33];
  const int tid = threadIdx.x;
  int b = blockIdx.x;
  if (b < 1536) {
    const int i = b * 256 + tid;
    const float4 a = *(const float4*)&x[(size_t)i * 8];
    const float4 c = *(const float4*)&x[(size_t)i * 8 + 4];
    u32x4 w = {pk2(a.x, a.y), pk2(a.z, a.w), pk2(c.x, c.y), pk2(c.z, c.w)};
    *(u32x4*)&xb[(size_t)i * 8] = w;
    return;
  }
  b -= 1536;
  const float* W;
  unsigned short* Wt;
  int N, nx;
  if (b < 1728) {
    W = w_attn; Wt = wtm; N = 2304; nx = 72;
  } else if (b < 1728 + 576) {
    b -= 1728; W = w_proj; Wt = wtp; N = 768; nx = 24;
  } else {
    b -= 1728 + 576; W = w_sel1; Wt = wtm + (size_t)2304 * 768; N = 192; nx = 6;
  }
  const int n0 = (b % nx) * 32, k0 = (b / nx) * 32;
  const int r = tid >> 5, c = tid & 31;
#pragma unroll
  for (int rr = 0; rr < 4; ++rr)
    t[r + 8 * rr][c] = W[(size_t)(k0 + r + 8 * rr) * N + n0 + c];
  __syncthreads();
#pragma unroll
  for (int rr = 0; rr < 4; ++rr)
    Wt[(size_t)(n0 + r + 8 * rr) * 768 + k0 + c] = b16(t[c][r + 8 * rr]);
}

// ---------------------------------------------------------------- merged qkv+sel GEMM
// C = x @ [w_attn | w_sel1 | pad], N=2560.  Epilogue routes per column:
// n<768: q -> *QS -> bf16 qkvb; n<2304: k/v -> bf16 qkvb;
// n<2496: gelu(+b_sel1) -> f32 ghbuf; else pad (discard).
__global__ __launch_bounds__(256) void qkvsel_gemm_kernel(
    const unsigned short* __restrict__ A, const unsigned short* __restrict__ Bt,
    const float* __restrict__ b_attn, const float* __restrict__ b_sel1,
    unsigned short* __restrict__ qkvb, float* __restrict__ ghbuf, int K) {
  __shared__ alignas(16) unsigned short as_[128 * 64];
  __shared__ alignas(16) unsigned short bs_[128 * 64];
  const int tid = threadIdx.x;
  const int lane = tid & 63;
  const int wv = tid >> 6;
  const int hi = lane >> 5;
  const int l31 = lane & 31;
  const int m0 = blockIdx.y * 128, n0 = blockIdx.x * 128;

  u32x4 ar[4], br[4];

#define G_ISSUE(K0)                                                           \
  do {                                                                        \
    _Pragma("unroll") for (int i = 0; i < 4; ++i) {                           \
      const int idx = tid + (i << 8);                                         \
      const int r = idx >> 3, c = idx & 7;                                    \
      ar[i] = *(const u32x4*)&A[(size_t)(m0 + r) * K + (K0) + c * 8];         \
      br[i] = *(const u32x4*)&Bt[(size_t)(n0 + r) * K + (K0) + c * 8];        \
    }                                                                         \
  } while (0)

#define G_WRITE()                                                             \
  do {                                                                        \
    _Pragma("unroll") for (int i = 0; i < 4; ++i) {                           \
      const int idx = tid + (i << 8);                                         \
      const int r = idx >> 3, c = idx & 7;                                    \
      *(u32x4*)((char*)as_ + r * 128 + ((c ^ (r & 7)) << 4)) = ar[i];         \
      *(u32x4*)((char*)bs_ + r * 128 + ((c ^ (r & 7)) << 4)) = br[i];         \
    }                                                                         \
  } while (0)

  f32x16 acc[4];
#pragma unroll
  for (int nt = 0; nt < 4; ++nt)
#pragma unroll
    for (int r = 0; r < 16; ++r) acc[nt][r] = 0.f;

  G_ISSUE(0);
  G_WRITE();
  __syncthreads();

  const int arow = wv * 32 + l31;
  for (int k0 = 0; k0 < K; k0 += 64) {
    if (k0 + 64 < K) G_ISSUE(k0 + 64);
#pragma unroll
    for (int s = 0; s < 4; ++s) {
      F4 af;
      af.u = *(const u32x4*)((const char*)as_ + arow * 128 +
                             (((2 * s + hi) ^ (arow & 7)) << 4));
#pragma unroll
      for (int nt = 0; nt < 4; ++nt) {
        F4 bf;
        bf.u = *(const u32x4*)((const char*)bs_ + (nt * 32 + l31) * 128 +
                               (((2 * s + hi) ^ (l31 & 7)) << 4));
        acc[nt] = __builtin_amdgcn_mfma_f32_32x32x16_bf16(af.h, bf.h, acc[nt], 0, 0, 0);
      }
    }
    __syncthreads();
    if (k0 + 64 < K) G_WRITE();
    __syncthreads();
  }

#pragma unroll
  for (int nt = 0; nt < 4; ++nt)
#pragma unroll
    for (int r = 0; r < 16; ++r) {
      const int m = m0 + wv * 32 + (r & 3) + 8 * (r >> 2) + 4 * hi;
      const int n = n0 + nt * 32 + l31;
      const float v = acc[nt][r];
      if (n < 768) {
        qkvb[(size_t)m * 2304 + n] = b16((v + b_attn[n]) * QS);
      } else if (n < 2304) {
        qkvb[(size_t)m * 2304 + n] = b16(v + b_attn[n]);
      } else if (n < 2496) {
        const float h = v + b_sel1[n - 2304];
        ghbuf[(size_t)m * 192 + (n - 2304)] =
            0.5f * h * (1.f + erff(h * 0.70710678118654752f));
      }
    }
#undef G_ISSUE
#undef G_WRITE
}

// ---------------------------------------------------------------- bf16 MFMA GEMM (proj)
template <int NT, bool OUTBF, int ACT>
__global__ __launch_bounds__(256) void gemm_mfma_kernel(
    const unsigned short* __restrict__ A, const unsigned short* __restrict__ Bt,
    const float* __restrict__ bias, void* __restrict__ Cout,
    int M, int N, int K) {
  __shared__ alignas(16) unsigned short as_[128 * 64];
  __shared__ alignas(16) unsigned short bs_[NT * 32 * 64];
  const int tid = threadIdx.x;
  const int lane = tid & 63;
  const int wv = tid >> 6;
  const int hi = lane >> 5;
  const int l31 = lane & 31;
  const int m0 = blockIdx.y * 128, n0 = blockIdx.x * (NT * 32);

  u32x4 ar[4], br[NT];

#define G_ISSUE(K0)                                                           \
  do {                                                                        \
    _Pragma("unroll") for (int i = 0; i < 4; ++i) {                           \
      const int idx = tid + (i << 8);                                         \
      const int r = idx >> 3, c = idx & 7;                                    \
      ar[i] = *(const u32x4*)&A[(size_t)(m0 + r) * K + (K0) + c * 8];         \
    }                                                                         \
    _Pragma("unroll") for (int i = 0; i < NT; ++i) {                          \
      const int idx = tid + (i << 8);                                         \
      const int r = idx >> 3, c = idx & 7;                                    \
      br[i] = *(const u32x4*)&Bt[(size_t)(n0 + r) * K + (K0) + c * 8];        \
    }                                                                         \
  } while (0)

#define G_WRITE()                                                             \
  do {                                                                        \
    _Pragma("unroll") for (int i = 0; i < 4; ++i) {                           \
      const int idx = tid + (i << 8);                                         \
      const int r = idx >> 3, c = idx & 7;                                    \
      *(u32x4*)((char*)as_ + r * 128 + ((c ^ (r & 7)) << 4)) = ar[i];         \
    }                                                                         \
    _Pragma("unroll") for (int i = 0; i < NT; ++i) {                          \
      const int idx = tid + (i << 8);                                         \
      const int r = idx >> 3, c = idx & 7;                                    \
      *(u32x4*)((char*)bs_ + r * 128 + ((c ^ (r & 7)) << 4)) = br[i];         \
    }                                                                         \
  } while (0)

  f32x16 acc[NT];
#pragma unroll
  for (int nt = 0; nt < NT; ++nt)
#pragma unroll
    for (int r = 0; r < 16; ++r) acc[nt][r] = 0.f;

  G_ISSUE(0);
  G_WRITE();
  __syncthreads();

  const int arow = wv * 32 + l31;
  for (int k0 = 0; k0 < K; k0 += 64) {
    if (k0 + 64 < K) G_ISSUE(k0 + 64);
#pragma unroll
    for (int s = 0; s < 4; ++s) {
      F4 af;
      af.u = *(const u32x4*)((const char*)as_ + arow * 128 +
                             (((2 * s + hi) ^ (arow & 7)) << 4));
#pragma unroll
      for (int nt = 0; nt < NT; ++nt) {
        F4 bf;
        bf.u = *(const u32x4*)((const char*)bs_ + (nt * 32 + l31) * 128 +
                               (((2 * s + hi) ^ (l31 & 7)) << 4));
        acc[nt] = __builtin_amdgcn_mfma_f32_32x32x16_bf16(af.h, bf.h, acc[nt], 0, 0, 0);
      }
    }
    __syncthreads();
    if (k0 + 64 < K) G_WRITE();
    __syncthreads();
  }

#pragma unroll
  for (int nt = 0; nt < NT; ++nt)
#pragma unroll
    for (int r = 0; r < 16; ++r) {
      const int m = m0 + wv * 32 + (r & 3) + 8 * (r >> 2) + 4 * hi;
      const int n = n0 + nt * 32 + l31;
      float v = acc[nt][r] + bias[n];
      if (ACT == 1) v = 0.5f * v * (1.f + erff(v * 0.70710678118654752f));
      if (OUTBF)
        ((unsigned short*)Cout)[(size_t)m * N + n] = b16(v);
      else
        ((float*)Cout)[(size_t)m * N + n] = v;
    }
#undef G_ISSUE
#undef G_WRITE
}

// ---------------------------------------------------------------- gate reduce
// NOTE: no 0.125*L2E here anymore — folded into Q at the GEMM epilogue.
__global__ __launch_bounds__(256) void gate_kernel(
    const float* __restrict__ gh, const float* __restrict__ w2,
    const float* __restrict__ b2, float* __restrict__ gate) {
  const int lane = threadIdx.x & 63;
  const int row = blockIdx.x * 4 + (threadIdx.x >> 6);
  float s = 0.f;
#pragma unroll
  for (int j = 0; j < 3; ++j) {
    const int c = lane + 64 * j;
    s = fmaf(gh[(size_t)row * 192 + c], w2[c], s);
  }
#pragma unroll
  for (int off = 32; off; off >>= 1) s += __shfl_xor(s, off, 64);
  if (lane == 0) {
    const float sel = 1.f / (1.f + __expf(-(s + b2[0])));
    gate[row] = 0.2f + 0.8f * sel;
  }
}

// ---------------------------------------------------------------- fused attention partials
// r13 champion structure; Q pre-scaled by QS so stream-1 needs no multiplies.
__global__ __launch_bounds__(256) void attn_part_kernel(
    const unsigned short* __restrict__ qkvb, const float* __restrict__ gate8,
    unsigned short* __restrict__ part1O, unsigned short* __restrict__ part2O,
    float* __restrict__ part2ML) {
  __shared__ alignas(16) unsigned short k_s[2][KB * 64];   // bf16, swizzled
  __shared__ alignas(16) unsigned short vt_s[2][64 * 68];  // V^T: row=d (68 u16)
  __shared__ float g_s[2][KB];

  const int tid = threadIdx.x;
  const int lane = tid & 63;
  const int wv = tid >> 6;
  const int hi = lane >> 5;
  const int l31 = lane & 31;
  const int vr2 = tid & 31;        // key-pair index (keys 2*vr2, 2*vr2+1)
  const int vc4 = tid >> 5;        // dim group (dims vc4*8 .. +7)
  const int bh = blockIdx.y;
  const int bb = bh / NHEAD;
  const int hh = bh % NHEAD;

  u32x4 kr[2], vr[2];
  float gr = 0.f;

#define A_ISSUE(T0, WG)                                                        \
  do {                                                                         \
    _Pragma("unroll") for (int i = 0; i < 2; ++i) {                            \
      const int idx = tid + (i << 8);                                          \
      const int r = idx >> 3, c = idx & 7;                                     \
      kr[i] = *(const u32x4*)&qkvb[(size_t)(bb * TT + (T0) + r) * 2304 +       \
                                   hh * 64 + 768 + c * 8];                     \
    }                                                                          \
    {                                                                          \
      const size_t vbase = (size_t)(bb * TT + (T0) + 2 * vr2) * 2304 +         \
                           hh * 64 + 1536 + vc4 * 8;                           \
      vr[0] = *(const u32x4*)&qkvb[vbase];                                     \
      vr[1] = *(const u32x4*)&qkvb[vbase + 2304];                              \
    }                                                                          \
    if (WG && tid < KB) gr = gate8[bb * TT + (T0) + tid];                      \
  } while (0)

#define A_WRITE(KD, VD, GD, WG)                                                \
  do {                                                                         \
    _Pragma("unroll") for (int i = 0; i < 2; ++i) {                            \
      const int idx = tid + (i << 8);                                          \
      const int r = idx >> 3, c = idx & 7;                                     \
      *(u32x4*)((char*)(KD) + r * 128 + ((c ^ (r & 7)) << 4)) = kr[i];         \
    }                                                                          \
    _Pragma("unroll") for (int k = 0; k < 8; ++k) {                            \
      const int j = k >> 1;                                                    \
      const u32 a0 = vr[0][j], a1 = vr[1][j];                                  \
      const u32 val = (k & 1) ? ((a0 >> 16) | (a1 & 0xffff0000u))              \
                              : ((a0 & 0xffffu) | (a1 << 16));                 \
      *(u32*)&(VD)[(vc4 * 8 + k) * 68 + 2 * vr2] = val;                        \
    }                                                                          \
    if (WG && tid < KB) (GD)[tid] = gr;                                        \
  } while (0)

#define QK_MFMA(KC)                                                            \
  do {                                                                         \
    _Pragma("unroll") for (int s = 0; s < 4; ++s) {                            \
      const int blk = (2 * s + hi) ^ (l31 & 7);                                \
      F4 f0, f1;                                                               \
      f0.u = *(const u32x4*)((const char*)(KC) + l31 * 128 + (blk << 4));      \
      f1.u = *(const u32x4*)((const char*)(KC) + (32 + l31) * 128 + (blk << 4));\
      S0 = __builtin_amdgcn_mfma_f32_32x32x16_bf16(f0.h, qf[s], S0, 0, 0, 0);  \
      S1 = __builtin_amdgcn_mfma_f32_32x32x16_bf16(f1.h, qf[s], S1, 0, 0, 0);  \
    }                                                                          \
  } while (0)

#define V_FRAGS(VC)                                                            \
  do {                                                                         \
    const char* vb0 = (const char*)(VC) + (size_t)l31 * 136 + hi * 8;          \
    const char* vb1 = vb0 + 32 * 136;                                          \
    _Pragma("unroll") for (int kb4 = 0; kb4 < 4; ++kb4) {                      \
      const u32x2 a0 = *(const u32x2*)(vb0 + 32 * kb4);                        \
      const u32x2 a1 = *(const u32x2*)(vb0 + 32 * kb4 + 16);                   \
      va[kb4].u = (u32x4){a0.x, a0.y, a1.x, a1.y};                             \
      const u32x2 c0 = *(const u32x2*)(vb1 + 32 * kb4);                        \
      const u32x2 c1 = *(const u32x2*)(vb1 + 32 * kb4 + 16);                   \
      vbf[kb4].u = (u32x4){c0.x, c0.y, c1.x, c1.y};                            \
    }                                                                          \
  } while (0)

// exp2-domain online softmax + PV with defer-rescale (THR=8).
#define SOFTMAX_PV(M, L, OA, OB)                                               \
  do {                                                                         \
    float red[8];                                                              \
    _Pragma("unroll") for (int i = 0; i < 8; ++i)                              \
      red[i] = fmaxf(fmaxf(S0[i], S0[i + 8]), fmaxf(S1[i], S1[i + 8]));        \
    _Pragma("unroll") for (int off = 4; off; off >>= 1)                        \
      _Pragma("unroll") for (int i = 0; i < off; ++i)                          \
        red[i] = fmaxf(red[i], red[i + off]);                                  \
    const float pmax = fmaxf(red[0], __shfl_xor(red[0], 32));                  \
    const int resc = __any(pmax > M + 8.f);                                    \
    float f = 1.f;                                                             \
    if (resc) {                                                                \
      const float mn = fmaxf(M, pmax);                                         \
      f = exp2f(M - mn);                                                       \
      M = mn;                                                                  \
    }                                                                          \
    _Pragma("unroll") for (int r = 0; r < 16; ++r) {                           \
      S0[r] = exp2f(S0[r] - M);                                                \
      S1[r] = exp2f(S1[r] - M);                                                \
    }                                                                          \
    _Pragma("unroll") for (int i = 0; i < 8; ++i)                              \
      red[i] = (S0[i] + S0[i + 8]) + (S1[i] + S1[i + 8]);                      \
    _Pragma("unroll") for (int off = 4; off; off >>= 1)                        \
      _Pragma("unroll") for (int i = 0; i < off; ++i)                          \
        red[i] += red[i + off];                                                \
    const float sum = red[0] + __shfl_xor(red[0], 32);                         \
    if (resc) {                                                                \
      L = L * f + sum;                                                         \
      _Pragma("unroll") for (int r = 0; r < 16; ++r) {                         \
        const float fq = __shfl(f, (r & 3) + 8 * (r >> 2) + 4 * hi);           \
        OA[r] *= fq;                                                           \
        OB[r] *= fq;                                                           \
      }                                                                        \
    } else {                                                                   \
      L += sum;                                                                \
    }                                                                          \
    u32 Pp[16];                                                                \
    _Pragma("unroll") for (int w = 0; w < 8; ++w) {                            \
      asm("v_cvt_pk_bf16_f32 %0, %1, %2" : "=v"(Pp[w]) : "v"(S0[2 * w]), "v"(S0[2 * w + 1])); \
      asm("v_cvt_pk_bf16_f32 %0, %1, %2" : "=v"(Pp[8 + w]) : "v"(S1[2 * w]), "v"(S1[2 * w + 1])); \
    }                                                                          \
    _Pragma("unroll") for (int kb4 = 0; kb4 < 4; ++kb4) {                      \
      F4 a;                                                                    \
      a.u = (u32x4){Pp[4 * kb4 + 0], Pp[4 * kb4 + 1], Pp[4 * kb4 + 2],         \
                    Pp[4 * kb4 + 3]};                                          \
      OA = __builtin_amdgcn_mfma_f32_32x32x16_bf16(a.h, va[kb4].h, OA, 0, 0, 0);\
      OB = __builtin_amdgcn_mfma_f32_32x32x16_bf16(a.h, vbf[kb4].h, OB, 0, 0, 0);\
    }                                                                          \
  } while (0)

  if (blockIdx.x >= 16) {
    // ================= stream 2: causal, gate-modulated, 4-tile chunks =====
    const int slot = (NSLOT - 1) - (blockIdx.x - 16);   // heavy slots first
    const int g = (slot < 2) ? 0 : (slot < 6) ? 1 : (slot < 12) ? 2 :
                  (slot < 20) ? 3 : (slot < 30) ? 4 : (slot < 42) ? 5 :
                  (slot < 56) ? 6 : 7;
    const int idxg = slot - g * (g + 1);
    const int e = (idxg >= g + 1) ? 1 : 0;
    const int qt = 2 * g + e;
    const int ch = idxg - e * (g + 1);
    const int r0 = qt * QBA;
    const int r0w = r0 + wv * 32;
    const int iq = r0w + l31;
    const int tlo = ch * 4;
    const int thi = min(tlo + 4, 2 * (qt + 1));

    bf16x8 qf[4];
    {
      const size_t qrow = (size_t)(bb * TT + r0w + l31) * 2304 + hh * 64;
#pragma unroll
      for (int s = 0; s < 4; ++s) {
        F4 f;
        f.u = *(const u32x4*)&qkvb[qrow + 16 * s + 8 * hi];
        qf[s] = f.h;
      }
    }

    float m2 = -1e30f, l2 = 0.f;
    f32x16 O2a, O2b;
#pragma unroll
    for (int r = 0; r < 16; ++r) { O2a[r] = 0.f; O2b[r] = 0.f; }

    A_ISSUE(tlo * 64, 1);
    A_WRITE(k_s[0], vt_s[0], g_s[0], 1);
    __syncthreads();

    int cur = 0;
    for (int t = tlo; t < thi; ++t) {
      const int t0 = t << 6;
      if (t + 1 < thi) A_ISSUE((t + 1) * 64, 1);
      if (t0 <= r0w + 31) {
        f32x16 S0, S1;
#pragma unroll
        for (int r = 0; r < 16; ++r) { S0[r] = 0.f; S1[r] = 0.f; }
        QK_MFMA(k_s[cur]);
        F4 va[4], vbf[4];
        V_FRAGS(vt_s[cur]);
        if (t0 + 63 <= r0w) {
          // interior: fully causal-valid for every lane of this wave
#pragma unroll
          for (int r = 0; r < 16; ++r) {
            const int crow = (r & 3) + 8 * (r >> 2) + 4 * hi;
            S0[r] *= g_s[cur][crow];
            S1[r] *= g_s[cur][32 + crow];
          }
        } else {
#pragma unroll
          for (int r = 0; r < 16; ++r) {
            const int crow = (r & 3) + 8 * (r >> 2) + 4 * hi;
            const int k0 = t0 + crow;
            S0[r] = (k0 <= iq) ? S0[r] * g_s[cur][crow] : -1e30f;
            S1[r] = (k0 + 32 <= iq) ? S1[r] * g_s[cur][32 + crow] : -1e30f;
          }
        }
        SOFTMAX_PV(m2, l2, O2a, O2b);
      }
      if (t + 1 < thi) A_WRITE(k_s[cur ^ 1], vt_s[cur ^ 1], g_s[cur ^ 1], 1);
      __syncthreads();
      cur ^= 1;
    }

    const size_t srow = ((size_t)bh * NSLOT + slot) * 128 + wv * 32;
    if (hi == 0) {
      float2 ml;
      ml.x = m2;
      ml.y = l2;
      *(float2*)&part2ML[(srow + l31) * 2] = ml;
    }
#pragma unroll
    for (int r = 0; r < 16; ++r) {
      const int crow = (r & 3) + 8 * (r >> 2) + 4 * hi;
      const size_t rowi = srow + crow;
      part2O[rowi * 64 + l31]      = b16(O2a[r]);
      part2O[rowi * 64 + 32 + l31] = b16(O2b[r]);
    }
  } else {
    // ================= stream 1: local window (launched first) =============
    const int qt = blockIdx.x;                   // 0..15
    const int r0 = qt * QBA;
    const int r0w = r0 + wv * 32;
    const int iq = r0w + l31;
    int tlo = (r0 - LWIN) >> 6;
    tlo = tlo < 0 ? 0 : tlo;
    const int thi = (r0 + QBA) >> 6;

    bf16x8 qf[4];
    {
      const size_t qrow = (size_t)(bb * TT + r0w + l31) * 2304 + hh * 64;
#pragma unroll
      for (int s = 0; s < 4; ++s) {
        F4 f;
        f.u = *(const u32x4*)&qkvb[qrow + 16 * s + 8 * hi];
        qf[s] = f.h;
      }
    }

    float m1 = -1e30f, l1 = 0.f;
    f32x16 O1a, O1b;
#pragma unroll
    for (int r = 0; r < 16; ++r) { O1a[r] = 0.f; O1b[r] = 0.f; }

    A_ISSUE(tlo * 64, 0);
    A_WRITE(k_s[0], vt_s[0], g_s[0], 0);
    __syncthreads();

    int cur = 0;
    for (int t = tlo; t < thi; ++t) {
      const int t0 = t << 6;
      if (t + 1 < thi) A_ISSUE((t + 1) * 64, 0);
      if (t0 + 63 >= r0w - LWIN && t0 <= r0w + 31) {
        f32x16 S0, S1;
#pragma unroll
        for (int r = 0; r < 16; ++r) { S0[r] = 0.f; S1[r] = 0.f; }
        QK_MFMA(k_s[cur]);
        F4 va[4], vbf[4];
        V_FRAGS(vt_s[cur]);
        // Q pre-scaled: interior tiles need NO scaling at all.
        if (!(t0 + 63 <= r0w && t0 >= r0w + 31 - LWIN)) {
#pragma unroll
          for (int r = 0; r < 16; ++r) {
            const int crow = (r & 3) + 8 * (r >> 2) + 4 * hi;
            const int k0 = t0 + crow;
            const bool ok0 = (k0 <= iq) && (k0 + LWIN >= iq);
            const bool ok1 = (k0 + 32 <= iq) && (k0 + 32 + LWIN >= iq);
            S0[r] = ok0 ? S0[r] : -1e30f;
            S1[r] = ok1 ? S1[r] : -1e30f;
          }
        }
        SOFTMAX_PV(m1, l1, O1a, O1b);
      }
      if (t + 1 < thi) A_WRITE(k_s[cur ^ 1], vt_s[cur ^ 1], g_s[cur ^ 1], 0);
      __syncthreads();
      cur ^= 1;
    }

    const size_t obase = (((size_t)bh * 16 + qt) * 128 + wv * 32) * 64;
#pragma unroll
    for (int r = 0; r < 16; ++r) {
      const int crow = (r & 3) + 8 * (r >> 2) + 4 * hi;
      const float inv = 1.f / __shfl(l1, crow);
      part1O[obase + (size_t)crow * 64 + l31]      = b16(O1a[r] * inv);
      part1O[obase + (size_t)crow * 64 + 32 + l31] = b16(O1b[r] * inv);
    }
  }
#undef A_ISSUE
#undef A_WRITE
#undef QK_MFMA
#undef V_FRAGS
#undef SOFTMAX_PV
}

// ---------------------------------------------------------------- combine partials
__global__ __launch_bounds__(256) void combine_kernel(
    const unsigned short* __restrict__ part1O,
    const unsigned short* __restrict__ part2O,
    const float* __restrict__ part2ML,
    const float* __restrict__ lwp, const float* __restrict__ gwp,
    unsigned short* __restrict__ aob) {
  const int t = blockIdx.x * 256 + threadIdx.x;   // [0, 24*2048*8)
  const int d8 = t & 7;
  const int rr = t >> 3;
  const int bh = rr >> 11;
  const int qrow = rr & 2047;
  const int qt = qrow >> 7, row = qrow & 127;
  const int g = qt >> 1;
  const int sb = g * (g + 1) + (qt & 1) * (g + 1);
  const int nc = g + 1;

  float m = -1e30f, l = 0.f;
  float oa[4], ob[4];
#pragma unroll
  for (int j = 0; j < 4; ++j) { oa[j] = 0.f; ob[j] = 0.f; }

  for (int c = 0; c < nc; ++c) {
    const size_t rowi = ((size_t)bh * NSLOT + sb + c) * 128 + row;
    const float2 ml = *(const float2*)&part2ML[rowi * 2];
    const u32x4 po = *(const u32x4*)&part2O[(rowi << 6) + 8 * d8];
    const float mn = fmaxf(m, ml.x);
    const float e0 = exp2f(m - mn), e1 = exp2f(ml.x - mn);
    l = l * e0 + ml.y * e1;
#pragma unroll
    for (int j = 0; j < 4; ++j) {
      oa[j] = oa[j] * e0 + __uint_as_float(po[j] << 16) * e1;
      ob[j] = ob[j] * e0 + __uint_as_float(po[j] & 0xffff0000u) * e1;
    }
    m = mn;
  }
  const u32x4 o1p = *(const u32x4*)&part1O[((((size_t)bh * 16 + qt) * 128 + row) << 6) + 8 * d8];
  const float wlr = 1.f / (1.f + __expf(-lwp[0]));
  const float wgr = 1.f / (1.f + __expf(-gwp[0]));
  const float wl = wlr / (wlr + wgr);
  const float wg = wgr / (wlr + wgr);
  const float s2 = wg / l;
  u32x4 outw;
#pragma unroll
  for (int j = 0; j < 4; ++j) {
    const float outa = wl * __uint_as_float(o1p[j] << 16) + oa[j] * s2;
    const float outb = wl * __uint_as_float(o1p[j] & 0xffff0000u) + ob[j] * s2;
    outw[j] = pk2(outa, outb);
  }
  const int bb = bh / NHEAD, hh = bh % NHEAD;
  *(u32x4*)&aob[(size_t)(bb * TT + qrow) * CC + hh * 64 + 8 * d8] = outw;
}

// ---------------------------------------------------------------- launch
extern "C" void kernel_launch(void* const* d_in, const int* in_sizes, int n_in,
                              void* d_out, int out_size, void* d_ws, size_t ws_size,
                              hipStream_t stream) {
  const float* x      = (const float*)d_in[0];
  const float* w_attn = (const float*)d_in[1];
  const float* b_attn = (const float*)d_in[2];
  const float* w_proj = (const float*)d_in[3];
  const float* b_proj = (const float*)d_in[4];
  const float* w_sel1 = (const float*)d_in[5];
  const float* b_sel1 = (const float*)d_in[6];
  const float* w_sel2 = (const float*)d_in[7];
  const float* b_sel2 = (const float*)d_in[8];
  const float* lw     = (const float*)d_in[9];
  const float* gw     = (const float*)d_in[10];
  float* out = (float*)d_out;

  // workspace carve
  unsigned short* qkvb  = (unsigned short*)d_ws;                 // 4096*2304 u16
  unsigned short* xb    = qkvb + (size_t)MROWS * 2304;           // 4096*768
  unsigned short* wtm   = xb + (size_t)MROWS * 768;              // 2560*768 (attn|sel1|pad)
  unsigned short* wtp   = wtm + (size_t)2560 * 768;              // 768*768
  unsigned short* aob   = wtp + (size_t)768 * 768;               // 4096*768
  unsigned short* part1O = aob + (size_t)MROWS * 768;            // 24*16*128*64
  unsigned short* part2O = part1O + (size_t)24 * 16 * 128 * 64;  // 24*72*128*64
  float* gatebuf = (float*)(part2O + (size_t)24 * NSLOT * 128 * 64);  // 4096 f32
  float* part2ML = gatebuf + MROWS;                              // 24*72*128*2 f32
  float* ghbuf   = part2ML + (size_t)24 * NSLOT * 128 * 2;       // 4096*192 f32

  prep_kernel<<<3984, 256, 0, stream>>>(x, xb, w_attn, wtm, w_proj, wtp, w_sel1);
  qkvsel_gemm_kernel<<<dim3(2560 / 128, MROWS / 128), 256, 0, stream>>>(
      xb, wtm, b_attn, b_sel1, qkvb, ghbuf, 768);
  gate_kernel<<<MROWS / 4, 256, 0, stream>>>(ghbuf, w_sel2, b_sel2, gatebuf);
  attn_part_kernel<<<dim3(NSLOT + 16, BBATCH * NHEAD), 256, 0, stream>>>(
      qkvb, gatebuf, part1O, part2O, part2ML);
  combine_kernel<<<(BBATCH * NHEAD * TT * 8) / 256, 256, 0, stream>>>(
      part1O, part2O, part2ML, lw, gw, aob);
  gemm_mfma_kernel<2, false, 0><<<dim3(768 / 64, MROWS / 128), 256, 0, stream>>>(
      aob, wtp, b_proj, out, MROWS, 768, 768);
}

// Round 18
// 136.008 us; speedup vs baseline: 1.2632x; 1.2632x over previous
//
#include <hip/hip_runtime.h>
#include <cmath>

#define TT    2048
#define CC    768
#define NHEAD 12
#define LWIN  256
#define BBATCH 2
#define MROWS 4096   // B*T
#define QBA   128    // query rows per q-tile (4 waves x 32)
#define KB    64     // keys per tile
#define NSLOT 72     // stream-2 chunks of 4 tiles
#define L2E   1.4426950408889634f

typedef unsigned int u32;
typedef u32 u32x2 __attribute__((ext_vector_type(2)));
typedef u32 u32x4 __attribute__((ext_vector_type(4)));
typedef short bf16x8 __attribute__((ext_vector_type(8)));
typedef float f32x16 __attribute__((ext_vector_type(16)));

union F4 { u32x4 u; bf16x8 h; };

__device__ __forceinline__ unsigned short b16(float a) {
  u32 u = __float_as_uint(a);
  return (unsigned short)((u + 0x7FFFu + ((u >> 16) & 1u)) >> 16);
}
__device__ __forceinline__ u32 pk2(float a, float b) {
  return (u32)b16(a) | ((u32)b16(b) << 16);
}

// ---------------------------------------------------------------- fused prep
// blocks [0,1536): x -> bf16. [1536,3264): w_attn^T -> wtm rows 0..2303.
// [3264,3840): w_proj^T -> wtp. [3840,3984): w_sel1^T -> wtm rows 2304..2495.
__global__ __launch_bounds__(256) void prep_kernel(
    const float* __restrict__ x, unsigned short* __restrict__ xb,
    const float* __restrict__ w_attn, unsigned short* __restrict__ wtm,
    const float* __restrict__ w_proj, unsigned short* __restrict__ wtp,
    const float* __restrict__ w_sel1) {
  __shared__ float t[32][33];
  const int tid = threadIdx.x;
  int b = blockIdx.x;
  if (b < 1536) {
    const int i = b * 256 + tid;
    const float4 a = *(const float4*)&x[(size_t)i * 8];
    const float4 c = *(const float4*)&x[(size_t)i * 8 + 4];
    u32x4 w = {pk2(a.x, a.y), pk2(a.z, a.w), pk2(c.x, c.y), pk2(c.z, c.w)};
    *(u32x4*)&xb[(size_t)i * 8] = w;
    return;
  }
  b -= 1536;
  const float* W;
  unsigned short* Wt;
  int N, nx;
  if (b < 1728) {
    W = w_attn; Wt = wtm; N = 2304; nx = 72;
  } else if (b < 1728 + 576) {
    b -= 1728; W = w_proj; Wt = wtp; N = 768; nx = 24;
  } else {
    b -= 1728 + 576; W = w_sel1; Wt = wtm + (size_t)2304 * 768; N = 192; nx = 6;
  }
  const int n0 = (b % nx) * 32, k0 = (b / nx) * 32;
  const int r = tid >> 5, c = tid & 31;
#pragma unroll
  for (int rr = 0; rr < 4; ++rr)
    t[r + 8 * rr][c] = W[(size_t)(k0 + r + 8 * rr) * N + n0 + c];
  __syncthreads();
#pragma unroll
  for (int rr = 0; rr < 4; ++rr)
    Wt[(size_t)(n0 + r + 8 * rr) * 768 + k0 + c] = b16(t[c][r + 8 * rr]);
}

// ---------------------------------------------------------------- merged qkv+sel GEMM
// C = x @ [w_attn | w_sel1 | pad], N=2560.  Epilogue routes per column:
// n<2304: qkv -> bf16 qkvb; n<2496: gelu(+b_sel1) -> f32 ghbuf; else discard.
__global__ __launch_bounds__(256) void qkvsel_gemm_kernel(
    const unsigned short* __restrict__ A, const unsigned short* __restrict__ Bt,
    const float* __restrict__ b_attn, const float* __restrict__ b_sel1,
    unsigned short* __restrict__ qkvb, float* __restrict__ ghbuf, int K) {
  __shared__ alignas(16) unsigned short as_[128 * 64];
  __shared__ alignas(16) unsigned short bs_[128 * 64];
  const int tid = threadIdx.x;
  const int lane = tid & 63;
  const int wv = tid >> 6;
  const int hi = lane >> 5;
  const int l31 = lane & 31;
  const int m0 = blockIdx.y * 128, n0 = blockIdx.x * 128;

  u32x4 ar[4], br[4];

#define G_ISSUE(K0)                                                           \
  do {                                                                        \
    _Pragma("unroll") for (int i = 0; i < 4; ++i) {                           \
      const int idx = tid + (i << 8);                                         \
      const int r = idx >> 3, c = idx & 7;                                    \
      ar[i] = *(const u32x4*)&A[(size_t)(m0 + r) * K + (K0) + c * 8];         \
      br[i] = *(const u32x4*)&Bt[(size_t)(n0 + r) * K + (K0) + c * 8];        \
    }                                                                         \
  } while (0)

#define G_WRITE()                                                             \
  do {                                                                        \
    _Pragma("unroll") for (int i = 0; i < 4; ++i) {                           \
      const int idx = tid + (i << 8);                                         \
      const int r = idx >> 3, c = idx & 7;                                    \
      *(u32x4*)((char*)as_ + r * 128 + ((c ^ (r & 7)) << 4)) = ar[i];         \
      *(u32x4*)((char*)bs_ + r * 128 + ((c ^ (r & 7)) << 4)) = br[i];         \
    }                                                                         \
  } while (0)

  f32x16 acc[4];
#pragma unroll
  for (int nt = 0; nt < 4; ++nt)
#pragma unroll
    for (int r = 0; r < 16; ++r) acc[nt][r] = 0.f;

  G_ISSUE(0);
  G_WRITE();
  __syncthreads();

  const int arow = wv * 32 + l31;
  for (int k0 = 0; k0 < K; k0 += 64) {
    if (k0 + 64 < K) G_ISSUE(k0 + 64);
#pragma unroll
    for (int s = 0; s < 4; ++s) {
      F4 af;
      af.u = *(const u32x4*)((const char*)as_ + arow * 128 +
                             (((2 * s + hi) ^ (arow & 7)) << 4));
#pragma unroll
      for (int nt = 0; nt < 4; ++nt) {
        F4 bf;
        bf.u = *(const u32x4*)((const char*)bs_ + (nt * 32 + l31) * 128 +
                               (((2 * s + hi) ^ (l31 & 7)) << 4));
        acc[nt] = __builtin_amdgcn_mfma_f32_32x32x16_bf16(af.h, bf.h, acc[nt], 0, 0, 0);
      }
    }
    __syncthreads();
    if (k0 + 64 < K) G_WRITE();
    __syncthreads();
  }

#pragma unroll
  for (int nt = 0; nt < 4; ++nt)
#pragma unroll
    for (int r = 0; r < 16; ++r) {
      const int m = m0 + wv * 32 + (r & 3) + 8 * (r >> 2) + 4 * hi;
      const int n = n0 + nt * 32 + l31;
      const float v = acc[nt][r];
      if (n < 2304) {
        qkvb[(size_t)m * 2304 + n] = b16(v + b_attn[n]);
      } else if (n < 2496) {
        const float h = v + b_sel1[n - 2304];
        ghbuf[(size_t)m * 192 + (n - 2304)] =
            0.5f * h * (1.f + erff(h * 0.70710678118654752f));
      }
    }
#undef G_ISSUE
#undef G_WRITE
}

// ---------------------------------------------------------------- bf16 MFMA GEMM (proj)
template <int NT, bool OUTBF, int ACT>
__global__ __launch_bounds__(256) void gemm_mfma_kernel(
    const unsigned short* __restrict__ A, const unsigned short* __restrict__ Bt,
    const float* __restrict__ bias, void* __restrict__ Cout,
    int M, int N, int K) {
  __shared__ alignas(16) unsigned short as_[128 * 64];
  __shared__ alignas(16) unsigned short bs_[NT * 32 * 64];
  const int tid = threadIdx.x;
  const int lane = tid & 63;
  const int wv = tid >> 6;
  const int hi = lane >> 5;
  const int l31 = lane & 31;
  const int m0 = blockIdx.y * 128, n0 = blockIdx.x * (NT * 32);

  u32x4 ar[4], br[NT];

#define G_ISSUE(K0)                                                           \
  do {                                                                        \
    _Pragma("unroll") for (int i = 0; i < 4; ++i) {                           \
      const int idx = tid + (i << 8);                                         \
      const int r = idx >> 3, c = idx & 7;                                    \
      ar[i] = *(const u32x4*)&A[(size_t)(m0 + r) * K + (K0) + c * 8];         \
    }                                                                         \
    _Pragma("unroll") for (int i = 0; i < NT; ++i) {                          \
      const int idx = tid + (i << 8);                                         \
      const int r = idx >> 3, c = idx & 7;                                    \
      br[i] = *(const u32x4*)&Bt[(size_t)(n0 + r) * K + (K0) + c * 8];        \
    }                                                                         \
  } while (0)

#define G_WRITE()                                                             \
  do {                                                                        \
    _Pragma("unroll") for (int i = 0; i < 4; ++i) {                           \
      const int idx = tid + (i << 8);                                         \
      const int r = idx >> 3, c = idx & 7;                                    \
      *(u32x4*)((char*)as_ + r * 128 + ((c ^ (r & 7)) << 4)) = ar[i];         \
    }                                                                         \
    _Pragma("unroll") for (int i = 0; i < NT; ++i) {                          \
      const int idx = tid + (i << 8);                                         \
      const int r = idx >> 3, c = idx & 7;                                    \
      *(u32x4*)((char*)bs_ + r * 128 + ((c ^ (r & 7)) << 4)) = br[i];         \
    }                                                                         \
  } while (0)

  f32x16 acc[NT];
#pragma unroll
  for (int nt = 0; nt < NT; ++nt)
#pragma unroll
    for (int r = 0; r < 16; ++r) acc[nt][r] = 0.f;

  G_ISSUE(0);
  G_WRITE();
  __syncthreads();

  const int arow = wv * 32 + l31;
  for (int k0 = 0; k0 < K; k0 += 64) {
    if (k0 + 64 < K) G_ISSUE(k0 + 64);
#pragma unroll
    for (int s = 0; s < 4; ++s) {
      F4 af;
      af.u = *(const u32x4*)((const char*)as_ + arow * 128 +
                             (((2 * s + hi) ^ (arow & 7)) << 4));
#pragma unroll
      for (int nt = 0; nt < NT; ++nt) {
        F4 bf;
        bf.u = *(const u32x4*)((const char*)bs_ + (nt * 32 + l31) * 128 +
                               (((2 * s + hi) ^ (l31 & 7)) << 4));
        acc[nt] = __builtin_amdgcn_mfma_f32_32x32x16_bf16(af.h, bf.h, acc[nt], 0, 0, 0);
      }
    }
    __syncthreads();
    if (k0 + 64 < K) G_WRITE();
    __syncthreads();
  }

#pragma unroll
  for (int nt = 0; nt < NT; ++nt)
#pragma unroll
    for (int r = 0; r < 16; ++r) {
      const int m = m0 + wv * 32 + (r & 3) + 8 * (r >> 2) + 4 * hi;
      const int n = n0 + nt * 32 + l31;
      float v = acc[nt][r] + bias[n];
      if (ACT == 1) v = 0.5f * v * (1.f + erff(v * 0.70710678118654752f));
      if (OUTBF)
        ((unsigned short*)Cout)[(size_t)m * N + n] = b16(v);
      else
        ((float*)Cout)[(size_t)m * N + n] = v;
    }
#undef G_ISSUE
#undef G_WRITE
}

// ---------------------------------------------------------------- gate reduce
__global__ __launch_bounds__(256) void gate_kernel(
    const float* __restrict__ gh, const float* __restrict__ w2,
    const float* __restrict__ b2, float* __restrict__ gate) {
  const int lane = threadIdx.x & 63;
  const int row = blockIdx.x * 4 + (threadIdx.x >> 6);
  float s = 0.f;
#pragma unroll
  for (int j = 0; j < 3; ++j) {
    const int c = lane + 64 * j;
    s = fmaf(gh[(size_t)row * 192 + c], w2[c], s);
  }
#pragma unroll
  for (int off = 32; off; off >>= 1) s += __shfl_xor(s, off, 64);
  if (lane == 0) {
    const float sel = 1.f / (1.f + __expf(-(s + b2[0])));
    gate[row] = 0.125f * L2E * (0.2f + 0.8f * sel);
  }
}

// ---------------------------------------------------------------- fused attention partials
// r10 structure (max-tracked partials, VGPR<=128). V staged as key-PAIR u32
// writes: banks = (34d + r2) mod 32 -> 2 lanes/bank (free), vs 8-way before.
__global__ __launch_bounds__(256) void attn_part_kernel(
    const unsigned short* __restrict__ qkvb, const float* __restrict__ gate8,
    unsigned short* __restrict__ part1O, unsigned short* __restrict__ part2O,
    float* __restrict__ part2ML) {
  __shared__ alignas(16) unsigned short k_s[2][KB * 64];   // bf16, swizzled
  __shared__ alignas(16) unsigned short vt_s[2][64 * 68];  // V^T: row=d (68 u16)
  __shared__ float g_s[2][KB];

  const int tid = threadIdx.x;
  const int lane = tid & 63;
  const int wv = tid >> 6;
  const int hi = lane >> 5;
  const int l31 = lane & 31;
  const int vr2 = tid & 31;        // key-pair index (keys 2*vr2, 2*vr2+1)
  const int vc4 = tid >> 5;        // dim group (dims vc4*8 .. +7)
  const int bh = blockIdx.y;
  const int bb = bh / NHEAD;
  const int hh = bh % NHEAD;

  u32x4 kr[2], vr[2];
  float gr = 0.f;

#define A_ISSUE(T0, WG)                                                        \
  do {                                                                         \
    _Pragma("unroll") for (int i = 0; i < 2; ++i) {                            \
      const int idx = tid + (i << 8);                                          \
      const int r = idx >> 3, c = idx & 7;                                     \
      kr[i] = *(const u32x4*)&qkvb[(size_t)(bb * TT + (T0) + r) * 2304 +       \
                                   hh * 64 + 768 + c * 8];                     \
    }                                                                          \
    {                                                                          \
      const size_t vbase = (size_t)(bb * TT + (T0) + 2 * vr2) * 2304 +         \
                           hh * 64 + 1536 + vc4 * 8;                           \
      vr[0] = *(const u32x4*)&qkvb[vbase];                                     \
      vr[1] = *(const u32x4*)&qkvb[vbase + 2304];                              \
    }                                                                          \
    if (WG && tid < KB) gr = gate8[bb * TT + (T0) + tid];                      \
  } while (0)

#define A_WRITE(KD, VD, GD, WG)                                                \
  do {                                                                         \
    _Pragma("unroll") for (int i = 0; i < 2; ++i) {                            \
      const int idx = tid + (i << 8);                                          \
      const int r = idx >> 3, c = idx & 7;                                     \
      *(u32x4*)((char*)(KD) + r * 128 + ((c ^ (r & 7)) << 4)) = kr[i];         \
    }                                                                          \
    _Pragma("unroll") for (int k = 0; k < 8; ++k) {                            \
      const int j = k >> 1;                                                    \
      const u32 a0 = vr[0][j], a1 = vr[1][j];                                  \
      const u32 val = (k & 1) ? ((a0 >> 16) | (a1 & 0xffff0000u))              \
                              : ((a0 & 0xffffu) | (a1 << 16));                 \
      *(u32*)&(VD)[(vc4 * 8 + k) * 68 + 2 * vr2] = val;                        \
    }                                                                          \
    if (WG && tid < KB) (GD)[tid] = gr;                                        \
  } while (0)

#define QK_MFMA(KC)                                                            \
  do {                                                                         \
    _Pragma("unroll") for (int s = 0; s < 4; ++s) {                            \
      const int blk = (2 * s + hi) ^ (l31 & 7);                                \
      F4 f0, f1;                                                               \
      f0.u = *(const u32x4*)((const char*)(KC) + l31 * 128 + (blk << 4));      \
      f1.u = *(const u32x4*)((const char*)(KC) + (32 + l31) * 128 + (blk << 4));\
      S0 = __builtin_amdgcn_mfma_f32_32x32x16_bf16(f0.h, qf[s], S0, 0, 0, 0);  \
      S1 = __builtin_amdgcn_mfma_f32_32x32x16_bf16(f1.h, qf[s], S1, 0, 0, 0);  \
    }                                                                          \
  } while (0)

#define V_FRAGS(VC)                                                            \
  do {                                                                         \
    const char* vb0 = (const char*)(VC) + (size_t)l31 * 136 + hi * 8;          \
    const char* vb1 = vb0 + 32 * 136;                                          \
    _Pragma("unroll") for (int kb4 = 0; kb4 < 4; ++kb4) {                      \
      const u32x2 a0 = *(const u32x2*)(vb0 + 32 * kb4);                        \
      const u32x2 a1 = *(const u32x2*)(vb0 + 32 * kb4 + 16);                   \
      va[kb4].u = (u32x4){a0.x, a0.y, a1.x, a1.y};                             \
      const u32x2 c0 = *(const u32x2*)(vb1 + 32 * kb4);                        \
      const u32x2 c1 = *(const u32x2*)(vb1 + 32 * kb4 + 16);                   \
      vbf[kb4].u = (u32x4){c0.x, c0.y, c1.x, c1.y};                            \
    }                                                                          \
  } while (0)

// exp2-domain online softmax + PV with defer-rescale (THR=8).
#define SOFTMAX_PV(M, L, OA, OB)                                               \
  do {                                                                         \
    float red[8];                                                              \
    _Pragma("unroll") for (int i = 0; i < 8; ++i)                              \
      red[i] = fmaxf(fmaxf(S0[i], S0[i + 8]), fmaxf(S1[i], S1[i + 8]));        \
    _Pragma("unroll") for (int off = 4; off; off >>= 1)                        \
      _Pragma("unroll") for (int i = 0; i < off; ++i)                          \
        red[i] = fmaxf(red[i], red[i + off]);                                  \
    const float pmax = fmaxf(red[0], __shfl_xor(red[0], 32));                  \
    const int resc = __any(pmax > M + 8.f);                                    \
    float f = 1.f;                                                             \
    if (resc) {                                                                \
      const float mn = fmaxf(M, pmax);                                         \
      f = exp2f(M - mn);                                                       \
      M = mn;                                                                  \
    }                                                                          \
    _Pragma("unroll") for (int r = 0; r < 16; ++r) {                           \
      S0[r] = exp2f(S0[r] - M);                                                \
      S1[r] = exp2f(S1[r] - M);                                                \
    }                                                                          \
    _Pragma("unroll") for (int i = 0; i < 8; ++i)                              \
      red[i] = (S0[i] + S0[i + 8]) + (S1[i] + S1[i + 8]);                      \
    _Pragma("unroll") for (int off = 4; off; off >>= 1)                        \
      _Pragma("unroll") for (int i = 0; i < off; ++i)                          \
        red[i] += red[i + off];                                                \
    const float sum = red[0] + __shfl_xor(red[0], 32);                         \
    if (resc) {                                                                \
      L = L * f + sum;                                                         \
      _Pragma("unroll") for (int r = 0; r < 16; ++r) {                         \
        const float fq = __shfl(f, (r & 3) + 8 * (r >> 2) + 4 * hi);           \
        OA[r] *= fq;                                                           \
        OB[r] *= fq;                                                           \
      }                                                                        \
    } else {                                                                   \
      L += sum;                                                                \
    }                                                                          \
    u32 Pp[16];                                                                \
    _Pragma("unroll") for (int w = 0; w < 8; ++w) {                            \
      asm("v_cvt_pk_bf16_f32 %0, %1, %2" : "=v"(Pp[w]) : "v"(S0[2 * w]), "v"(S0[2 * w + 1])); \
      asm("v_cvt_pk_bf16_f32 %0, %1, %2" : "=v"(Pp[8 + w]) : "v"(S1[2 * w]), "v"(S1[2 * w + 1])); \
    }                                                                          \
    _Pragma("unroll") for (int kb4 = 0; kb4 < 4; ++kb4) {                      \
      F4 a;                                                                    \
      a.u = (u32x4){Pp[4 * kb4 + 0], Pp[4 * kb4 + 1], Pp[4 * kb4 + 2],         \
                    Pp[4 * kb4 + 3]};                                          \
      OA = __builtin_amdgcn_mfma_f32_32x32x16_bf16(a.h, va[kb4].h, OA, 0, 0, 0);\
      OB = __builtin_amdgcn_mfma_f32_32x32x16_bf16(a.h, vbf[kb4].h, OB, 0, 0, 0);\
    }                                                                          \
  } while (0)

  if (blockIdx.x >= 16) {
    // ================= stream 2: causal, gate-modulated, 4-tile chunks =====
    const int slot = (NSLOT - 1) - (blockIdx.x - 16);   // heavy slots first
    const int g = (slot < 2) ? 0 : (slot < 6) ? 1 : (slot < 12) ? 2 :
                  (slot < 20) ? 3 : (slot < 30) ? 4 : (slot < 42) ? 5 :
                  (slot < 56) ? 6 : 7;
    const int idxg = slot - g * (g + 1);
    const int e = (idxg >= g + 1) ? 1 : 0;
    const int qt = 2 * g + e;
    const int ch = idxg - e * (g + 1);
    const int r0 = qt * QBA;
    const int r0w = r0 + wv * 32;
    const int iq = r0w + l31;
    const int tlo = ch * 4;
    const int thi = min(tlo + 4, 2 * (qt + 1));

    bf16x8 qf[4];
    {
      const size_t qrow = (size_t)(bb * TT + r0w + l31) * 2304 + hh * 64;
#pragma unroll
      for (int s = 0; s < 4; ++s) {
        F4 f;
        f.u = *(const u32x4*)&qkvb[qrow + 16 * s + 8 * hi];
        qf[s] = f.h;
      }
    }

    float m2 = -1e30f, l2 = 0.f;
    f32x16 O2a, O2b;
#pragma unroll
    for (int r = 0; r < 16; ++r) { O2a[r] = 0.f; O2b[r] = 0.f; }

    A_ISSUE(tlo * 64, 1);
    A_WRITE(k_s[0], vt_s[0], g_s[0], 1);
    __syncthreads();

    int cur = 0;
    for (int t = tlo; t < thi; ++t) {
      const int t0 = t << 6;
      if (t + 1 < thi) A_ISSUE((t + 1) * 64, 1);
      if (t0 <= r0w + 31) {
        f32x16 S0, S1;
#pragma unroll
        for (int r = 0; r < 16; ++r) { S0[r] = 0.f; S1[r] = 0.f; }
        QK_MFMA(k_s[cur]);
        F4 va[4], vbf[4];
        V_FRAGS(vt_s[cur]);
        if (t0 + 63 <= r0w) {
          // interior: fully causal-valid for every lane of this wave
#pragma unroll
          for (int r = 0; r < 16; ++r) {
            const int crow = (r & 3) + 8 * (r >> 2) + 4 * hi;
            S0[r] *= g_s[cur][crow];
            S1[r] *= g_s[cur][32 + crow];
          }
        } else {
#pragma unroll
          for (int r = 0; r < 16; ++r) {
            const int crow = (r & 3) + 8 * (r >> 2) + 4 * hi;
            const int k0 = t0 + crow;
            S0[r] = (k0 <= iq) ? S0[r] * g_s[cur][crow] : -1e30f;
            S1[r] = (k0 + 32 <= iq) ? S1[r] * g_s[cur][32 + crow] : -1e30f;
          }
        }
        SOFTMAX_PV(m2, l2, O2a, O2b);
      }
      if (t + 1 < thi) A_WRITE(k_s[cur ^ 1], vt_s[cur ^ 1], g_s[cur ^ 1], 1);
      __syncthreads();
      cur ^= 1;
    }

    const size_t srow = ((size_t)bh * NSLOT + slot) * 128 + wv * 32;
    if (hi == 0) {
      float2 ml;
      ml.x = m2;
      ml.y = l2;
      *(float2*)&part2ML[(srow + l31) * 2] = ml;
    }
#pragma unroll
    for (int r = 0; r < 16; ++r) {
      const int crow = (r & 3) + 8 * (r >> 2) + 4 * hi;
      const size_t rowi = srow + crow;
      part2O[rowi * 64 + l31]      = b16(O2a[r]);
      part2O[rowi * 64 + 32 + l31] = b16(O2b[r]);
    }
  } else {
    // ================= stream 1: local window, raw scores (launched first) =
    const int qt = blockIdx.x;                   // 0..15
    const int r0 = qt * QBA;
    const int r0w = r0 + wv * 32;
    const int iq = r0w + l31;
    int tlo = (r0 - LWIN) >> 6;
    tlo = tlo < 0 ? 0 : tlo;
    const int thi = (r0 + QBA) >> 6;

    bf16x8 qf[4];
    {
      const size_t qrow = (size_t)(bb * TT + r0w + l31) * 2304 + hh * 64;
#pragma unroll
      for (int s = 0; s < 4; ++s) {
        F4 f;
        f.u = *(const u32x4*)&qkvb[qrow + 16 * s + 8 * hi];
        qf[s] = f.h;
      }
    }

    float m1 = -1e30f, l1 = 0.f;
    f32x16 O1a, O1b;
#pragma unroll
    for (int r = 0; r < 16; ++r) { O1a[r] = 0.f; O1b[r] = 0.f; }

    A_ISSUE(tlo * 64, 0);
    A_WRITE(k_s[0], vt_s[0], g_s[0], 0);
    __syncthreads();

    int cur = 0;
    for (int t = tlo; t < thi; ++t) {
      const int t0 = t << 6;
      if (t + 1 < thi) A_ISSUE((t + 1) * 64, 0);
      if (t0 + 63 >= r0w - LWIN && t0 <= r0w + 31) {
        f32x16 S0, S1;
#pragma unroll
        for (int r = 0; r < 16; ++r) { S0[r] = 0.f; S1[r] = 0.f; }
        QK_MFMA(k_s[cur]);
        F4 va[4], vbf[4];
        V_FRAGS(vt_s[cur]);
        if (t0 + 63 <= r0w && t0 >= r0w + 31 - LWIN) {
          // interior: every (row, key) of this wave inside the window
#pragma unroll
          for (int r = 0; r < 16; ++r) {
            S0[r] *= (0.125f * L2E);
            S1[r] *= (0.125f * L2E);
          }
        } else {
#pragma unroll
          for (int r = 0; r < 16; ++r) {
            const int crow = (r & 3) + 8 * (r >> 2) + 4 * hi;
            const int k0 = t0 + crow;
            const bool ok0 = (k0 <= iq) && (k0 + LWIN >= iq);
            const bool ok1 = (k0 + 32 <= iq) && (k0 + 32 + LWIN >= iq);
            S0[r] = ok0 ? S0[r] * (0.125f * L2E) : -1e30f;
            S1[r] = ok1 ? S1[r] * (0.125f * L2E) : -1e30f;
          }
        }
        SOFTMAX_PV(m1, l1, O1a, O1b);
      }
      if (t + 1 < thi) A_WRITE(k_s[cur ^ 1], vt_s[cur ^ 1], g_s[cur ^ 1], 0);
      __syncthreads();
      cur ^= 1;
    }

    const size_t obase = (((size_t)bh * 16 + qt) * 128 + wv * 32) * 64;
#pragma unroll
    for (int r = 0; r < 16; ++r) {
      const int crow = (r & 3) + 8 * (r >> 2) + 4 * hi;
      const float inv = 1.f / __shfl(l1, crow);
      part1O[obase + (size_t)crow * 64 + l31]      = b16(O1a[r] * inv);
      part1O[obase + (size_t)crow * 64 + 32 + l31] = b16(O1b[r] * inv);
    }
  }
#undef A_ISSUE
#undef A_WRITE
#undef QK_MFMA
#undef V_FRAGS
#undef SOFTMAX_PV
}

// ---------------------------------------------------------------- combine partials
// one thread = (bh, qrow, 8-d group): u32x4 coalesced IO, ml loaded once per chunk.
__global__ __launch_bounds__(256) void combine_kernel(
    const unsigned short* __restrict__ part1O,
    const unsigned short* __restrict__ part2O,
    const float* __restrict__ part2ML,
    const float* __restrict__ lwp, const float* __restrict__ gwp,
    unsigned short* __restrict__ aob) {
  const int t = blockIdx.x * 256 + threadIdx.x;   // [0, 24*2048*8)
  const int d8 = t & 7;
  const int rr = t >> 3;
  const int bh = rr >> 11;
  const int qrow = rr & 2047;
  const int qt = qrow >> 7, row = qrow & 127;
  const int g = qt >> 1;
  const int sb = g * (g + 1) + (qt & 1) * (g + 1);
  const int nc = g + 1;

  float m = -1e30f, l = 0.f;
  float oa[4], ob[4];
#pragma unroll
  for (int j = 0; j < 4; ++j) { oa[j] = 0.f; ob[j] = 0.f; }

  for (int c = 0; c < nc; ++c) {
    const size_t rowi = ((size_t)bh * NSLOT + sb + c) * 128 + row;
    const float2 ml = *(const float2*)&part2ML[rowi * 2];
    const u32x4 po = *(const u32x4*)&part2O[(rowi << 6) + 8 * d8];
    const float mn = fmaxf(m, ml.x);
    const float e0 = exp2f(m - mn), e1 = exp2f(ml.x - mn);
    l = l * e0 + ml.y * e1;
#pragma unroll
    for (int j = 0; j < 4; ++j) {
      oa[j] = oa[j] * e0 + __uint_as_float(po[j] << 16) * e1;
      ob[j] = ob[j] * e0 + __uint_as_float(po[j] & 0xffff0000u) * e1;
    }
    m = mn;
  }
  const u32x4 o1p = *(const u32x4*)&part1O[((((size_t)bh * 16 + qt) * 128 + row) << 6) + 8 * d8];
  const float wlr = 1.f / (1.f + __expf(-lwp[0]));
  const float wgr = 1.f / (1.f + __expf(-gwp[0]));
  const float wl = wlr / (wlr + wgr);
  const float wg = wgr / (wlr + wgr);
  const float s2 = wg / l;
  u32x4 outw;
#pragma unroll
  for (int j = 0; j < 4; ++j) {
    const float outa = wl * __uint_as_float(o1p[j] << 16) + oa[j] * s2;
    const float outb = wl * __uint_as_float(o1p[j] & 0xffff0000u) + ob[j] * s2;
    outw[j] = pk2(outa, outb);
  }
  const int bb = bh / NHEAD, hh = bh % NHEAD;
  *(u32x4*)&aob[(size_t)(bb * TT + qrow) * CC + hh * 64 + 8 * d8] = outw;
}

// ---------------------------------------------------------------- launch
extern "C" void kernel_launch(void* const* d_in, const int* in_sizes, int n_in,
                              void* d_out, int out_size, void* d_ws, size_t ws_size,
                              hipStream_t stream) {
  const float* x      = (const float*)d_in[0];
  const float* w_attn = (const float*)d_in[1];
  const float* b_attn = (const float*)d_in[2];
  const float* w_proj = (const float*)d_in[3];
  const float* b_proj = (const float*)d_in[4];
  const float* w_sel1 = (const float*)d_in[5];
  const float* b_sel1 = (const float*)d_in[6];
  const float* w_sel2 = (const float*)d_in[7];
  const float* b_sel2 = (const float*)d_in[8];
  const float* lw     = (const float*)d_in[9];
  const float* gw     = (const float*)d_in[10];
  float* out = (float*)d_out;

  // workspace carve
  unsigned short* qkvb  = (unsigned short*)d_ws;                 // 4096*2304 u16
  unsigned short* xb    = qkvb + (size_t)MROWS * 2304;           // 4096*768
  unsigned short* wtm   = xb + (size_t)MROWS * 768;              // 2560*768 (attn|sel1|pad)
  unsigned short* wtp   = wtm + (size_t)2560 * 768;              // 768*768
  unsigned short* aob   = wtp + (size_t)768 * 768;               // 4096*768
  unsigned short* part1O = aob + (size_t)MROWS * 768;            // 24*16*128*64
  unsigned short* part2O = part1O + (size_t)24 * 16 * 128 * 64;  // 24*72*128*64
  float* gatebuf = (float*)(part2O + (size_t)24 * NSLOT * 128 * 64);  // 4096 f32
  float* part2ML = gatebuf + MROWS;                              // 24*72*128*2 f32
  float* ghbuf   = part2ML + (size_t)24 * NSLOT * 128 * 2;       // 4096*192 f32

  prep_kernel<<<3984, 256, 0, stream>>>(x, xb, w_attn, wtm, w_proj, wtp, w_sel1);
  qkvsel_gemm_kernel<<<dim3(2560 / 128, MROWS / 128), 256, 0, stream>>>(
      xb, wtm, b_attn, b_sel1, qkvb, ghbuf, 768);
  gate_kernel<<<MROWS / 4, 256, 0, stream>>>(ghbuf, w_sel2, b_sel2, gatebuf);
  attn_part_kernel<<<dim3(NSLOT + 16, BBATCH * NHEAD), 256, 0, stream>>>(
      qkvb, gatebuf, part1O, part2O, part2ML);
  combine_kernel<<<(BBATCH * NHEAD * TT * 8) / 256, 256, 0, stream>>>(
      part1O, part2O, part2ML, lw, gw, aob);
  gemm_mfma_kernel<2, false, 0><<<dim3(768 / 64, MROWS / 128), 256, 0, stream>>>(
      aob, wtp, b_proj, out, MROWS, 768, 768);
}

// Round 19
// 131.236 us; speedup vs baseline: 1.3092x; 1.0364x over previous
//
#include <hip/hip_runtime.h>
#include <cmath>

#define TT    2048
#define CC    768
#define NHEAD 12
#define LWIN  256
#define BBATCH 2
#define MROWS 4096   // B*T
#define QBA   128    // query rows per q-tile (4 waves x 32)
#define KB    64     // keys per tile
#define NSLOT 72     // stream-2 chunks of 4 tiles
#define L2E   1.4426950408889634f

typedef unsigned int u32;
typedef u32 u32x2 __attribute__((ext_vector_type(2)));
typedef u32 u32x4 __attribute__((ext_vector_type(4)));
typedef short bf16x8 __attribute__((ext_vector_type(8)));
typedef float f32x16 __attribute__((ext_vector_type(16)));

union F4 { u32x4 u; bf16x8 h; };

__device__ __forceinline__ unsigned short b16(float a) {
  u32 u = __float_as_uint(a);
  return (unsigned short)((u + 0x7FFFu + ((u >> 16) & 1u)) >> 16);
}
__device__ __forceinline__ u32 pk2(float a, float b) {
  return (u32)b16(a) | ((u32)b16(b) << 16);
}

// ---------------------------------------------------------------- fused prep
// blocks [0,1536): x -> bf16. [1536,3264): w_attn^T -> wtm rows 0..2303.
// [3264,3840): w_proj^T -> wtp. [3840,3984): w_sel1^T -> wtm rows 2304..2495.
__global__ __launch_bounds__(256) void prep_kernel(
    const float* __restrict__ x, unsigned short* __restrict__ xb,
    const float* __restrict__ w_attn, unsigned short* __restrict__ wtm,
    const float* __restrict__ w_proj, unsigned short* __restrict__ wtp,
    const float* __restrict__ w_sel1) {
  __shared__ float t[32][33];
  const int tid = threadIdx.x;
  int b = blockIdx.x;
  if (b < 1536) {
    const int i = b * 256 + tid;
    const float4 a = *(const float4*)&x[(size_t)i * 8];
    const float4 c = *(const float4*)&x[(size_t)i * 8 + 4];
    u32x4 w = {pk2(a.x, a.y), pk2(a.z, a.w), pk2(c.x, c.y), pk2(c.z, c.w)};
    *(u32x4*)&xb[(size_t)i * 8] = w;
    return;
  }
  b -= 1536;
  const float* W;
  unsigned short* Wt;
  int N, nx;
  if (b < 1728) {
    W = w_attn; Wt = wtm; N = 2304; nx = 72;
  } else if (b < 1728 + 576) {
    b -= 1728; W = w_proj; Wt = wtp; N = 768; nx = 24;
  } else {
    b -= 1728 + 576; W = w_sel1; Wt = wtm + (size_t)2304 * 768; N = 192; nx = 6;
  }
  const int n0 = (b % nx) * 32, k0 = (b / nx) * 32;
  const int r = tid >> 5, c = tid & 31;
#pragma unroll
  for (int rr = 0; rr < 4; ++rr)
    t[r + 8 * rr][c] = W[(size_t)(k0 + r + 8 * rr) * N + n0 + c];
  __syncthreads();
#pragma unroll
  for (int rr = 0; rr < 4; ++rr)
    Wt[(size_t)(n0 + r + 8 * rr) * 768 + k0 + c] = b16(t[c][r + 8 * rr]);
}

// ---------------------------------------------------------------- merged qkv+sel GEMM
// C = x @ [w_attn | w_sel1 | pad], N=2560.  Epilogue routes per column:
// n<2304: qkv -> bf16 qkvb; n<2496: gelu(+b_sel1) -> f32 ghbuf; else discard.
__global__ __launch_bounds__(256) void qkvsel_gemm_kernel(
    const unsigned short* __restrict__ A, const unsigned short* __restrict__ Bt,
    const float* __restrict__ b_attn, const float* __restrict__ b_sel1,
    unsigned short* __restrict__ qkvb, float* __restrict__ ghbuf, int K) {
  __shared__ alignas(16) unsigned short as_[128 * 64];
  __shared__ alignas(16) unsigned short bs_[128 * 64];
  const int tid = threadIdx.x;
  const int lane = tid & 63;
  const int wv = tid >> 6;
  const int hi = lane >> 5;
  const int l31 = lane & 31;
  const int m0 = blockIdx.y * 128, n0 = blockIdx.x * 128;

  u32x4 ar[4], br[4];

#define G_ISSUE(K0)                                                           \
  do {                                                                        \
    _Pragma("unroll") for (int i = 0; i < 4; ++i) {                           \
      const int idx = tid + (i << 8);                                         \
      const int r = idx >> 3, c = idx & 7;                                    \
      ar[i] = *(const u32x4*)&A[(size_t)(m0 + r) * K + (K0) + c * 8];         \
      br[i] = *(const u32x4*)&Bt[(size_t)(n0 + r) * K + (K0) + c * 8];        \
    }                                                                         \
  } while (0)

#define G_WRITE()                                                             \
  do {                                                                        \
    _Pragma("unroll") for (int i = 0; i < 4; ++i) {                           \
      const int idx = tid + (i << 8);                                         \
      const int r = idx >> 3, c = idx & 7;                                    \
      *(u32x4*)((char*)as_ + r * 128 + ((c ^ (r & 7)) << 4)) = ar[i];         \
      *(u32x4*)((char*)bs_ + r * 128 + ((c ^ (r & 7)) << 4)) = br[i];         \
    }                                                                         \
  } while (0)

  f32x16 acc[4];
#pragma unroll
  for (int nt = 0; nt < 4; ++nt)
#pragma unroll
    for (int r = 0; r < 16; ++r) acc[nt][r] = 0.f;

  G_ISSUE(0);
  G_WRITE();
  __syncthreads();

  const int arow = wv * 32 + l31;
  for (int k0 = 0; k0 < K; k0 += 64) {
    if (k0 + 64 < K) G_ISSUE(k0 + 64);
#pragma unroll
    for (int s = 0; s < 4; ++s) {
      F4 af;
      af.u = *(const u32x4*)((const char*)as_ + arow * 128 +
                             (((2 * s + hi) ^ (arow & 7)) << 4));
#pragma unroll
      for (int nt = 0; nt < 4; ++nt) {
        F4 bf;
        bf.u = *(const u32x4*)((const char*)bs_ + (nt * 32 + l31) * 128 +
                               (((2 * s + hi) ^ (l31 & 7)) << 4));
        acc[nt] = __builtin_amdgcn_mfma_f32_32x32x16_bf16(af.h, bf.h, acc[nt], 0, 0, 0);
      }
    }
    __syncthreads();
    if (k0 + 64 < K) G_WRITE();
    __syncthreads();
  }

#pragma unroll
  for (int nt = 0; nt < 4; ++nt)
#pragma unroll
    for (int r = 0; r < 16; ++r) {
      const int m = m0 + wv * 32 + (r & 3) + 8 * (r >> 2) + 4 * hi;
      const int n = n0 + nt * 32 + l31;
      const float v = acc[nt][r];
      if (n < 2304) {
        qkvb[(size_t)m * 2304 + n] = b16(v + b_attn[n]);
      } else if (n < 2496) {
        const float h = v + b_sel1[n - 2304];
        ghbuf[(size_t)m * 192 + (n - 2304)] =
            0.5f * h * (1.f + erff(h * 0.70710678118654752f));
      }
    }
#undef G_ISSUE
#undef G_WRITE
}

// ---------------------------------------------------------------- bf16 MFMA GEMM (proj)
template <int NT, bool OUTBF, int ACT>
__global__ __launch_bounds__(256) void gemm_mfma_kernel(
    const unsigned short* __restrict__ A, const unsigned short* __restrict__ Bt,
    const float* __restrict__ bias, void* __restrict__ Cout,
    int M, int N, int K) {
  __shared__ alignas(16) unsigned short as_[128 * 64];
  __shared__ alignas(16) unsigned short bs_[NT * 32 * 64];
  const int tid = threadIdx.x;
  const int lane = tid & 63;
  const int wv = tid >> 6;
  const int hi = lane >> 5;
  const int l31 = lane & 31;
  const int m0 = blockIdx.y * 128, n0 = blockIdx.x * (NT * 32);

  u32x4 ar[4], br[NT];

#define G_ISSUE(K0)                                                           \
  do {                                                                        \
    _Pragma("unroll") for (int i = 0; i < 4; ++i) {                           \
      const int idx = tid + (i << 8);                                         \
      const int r = idx >> 3, c = idx & 7;                                    \
      ar[i] = *(const u32x4*)&A[(size_t)(m0 + r) * K + (K0) + c * 8];         \
    }                                                                         \
    _Pragma("unroll") for (int i = 0; i < NT; ++i) {                          \
      const int idx = tid + (i << 8);                                         \
      const int r = idx >> 3, c = idx & 7;                                    \
      br[i] = *(const u32x4*)&Bt[(size_t)(n0 + r) * K + (K0) + c * 8];        \
    }                                                                         \
  } while (0)

#define G_WRITE()                                                             \
  do {                                                                        \
    _Pragma("unroll") for (int i = 0; i < 4; ++i) {                           \
      const int idx = tid + (i << 8);                                         \
      const int r = idx >> 3, c = idx & 7;                                    \
      *(u32x4*)((char*)as_ + r * 128 + ((c ^ (r & 7)) << 4)) = ar[i];         \
    }                                                                         \
    _Pragma("unroll") for (int i = 0; i < NT; ++i) {                          \
      const int idx = tid + (i << 8);                                         \
      const int r = idx >> 3, c = idx & 7;                                    \
      *(u32x4*)((char*)bs_ + r * 128 + ((c ^ (r & 7)) << 4)) = br[i];         \
    }                                                                         \
  } while (0)

  f32x16 acc[NT];
#pragma unroll
  for (int nt = 0; nt < NT; ++nt)
#pragma unroll
    for (int r = 0; r < 16; ++r) acc[nt][r] = 0.f;

  G_ISSUE(0);
  G_WRITE();
  __syncthreads();

  const int arow = wv * 32 + l31;
  for (int k0 = 0; k0 < K; k0 += 64) {
    if (k0 + 64 < K) G_ISSUE(k0 + 64);
#pragma unroll
    for (int s = 0; s < 4; ++s) {
      F4 af;
      af.u = *(const u32x4*)((const char*)as_ + arow * 128 +
                             (((2 * s + hi) ^ (arow & 7)) << 4));
#pragma unroll
      for (int nt = 0; nt < NT; ++nt) {
        F4 bf;
        bf.u = *(const u32x4*)((const char*)bs_ + (nt * 32 + l31) * 128 +
                               (((2 * s + hi) ^ (l31 & 7)) << 4));
        acc[nt] = __builtin_amdgcn_mfma_f32_32x32x16_bf16(af.h, bf.h, acc[nt], 0, 0, 0);
      }
    }
    __syncthreads();
    if (k0 + 64 < K) G_WRITE();
    __syncthreads();
  }

#pragma unroll
  for (int nt = 0; nt < NT; ++nt)
#pragma unroll
    for (int r = 0; r < 16; ++r) {
      const int m = m0 + wv * 32 + (r & 3) + 8 * (r >> 2) + 4 * hi;
      const int n = n0 + nt * 32 + l31;
      float v = acc[nt][r] + bias[n];
      if (ACT == 1) v = 0.5f * v * (1.f + erff(v * 0.70710678118654752f));
      if (OUTBF)
        ((unsigned short*)Cout)[(size_t)m * N + n] = b16(v);
      else
        ((float*)Cout)[(size_t)m * N + n] = v;
    }
#undef G_ISSUE
#undef G_WRITE
}

// ---------------------------------------------------------------- gate reduce
__global__ __launch_bounds__(256) void gate_kernel(
    const float* __restrict__ gh, const float* __restrict__ w2,
    const float* __restrict__ b2, float* __restrict__ gate) {
  const int lane = threadIdx.x & 63;
  const int row = blockIdx.x * 4 + (threadIdx.x >> 6);
  float s = 0.f;
#pragma unroll
  for (int j = 0; j < 3; ++j) {
    const int c = lane + 64 * j;
    s = fmaf(gh[(size_t)row * 192 + c], w2[c], s);
  }
#pragma unroll
  for (int off = 32; off; off >>= 1) s += __shfl_xor(s, off, 64);
  if (lane == 0) {
    const float sel = 1.f / (1.f + __expf(-(s + b2[0])));
    gate[row] = 0.125f * L2E * (0.2f + 0.8f * sel);
  }
}

// ---------------------------------------------------------------- fused attention partials
// r13 champion loop body (frozen, VGPR=128). Grid TRANSPOSED to (24 bh, 88):
// x = bh is the fastest dispatch axis, so all 384 long stream-1 blocks
// (y<16) launch before any 4-tile stream-2 chunk -> uniform drain tail.
__global__ __launch_bounds__(256) void attn_part_kernel(
    const unsigned short* __restrict__ qkvb, const float* __restrict__ gate8,
    unsigned short* __restrict__ part1O, unsigned short* __restrict__ part2O,
    float* __restrict__ part2ML) {
  __shared__ alignas(16) unsigned short k_s[2][KB * 64];   // bf16, swizzled
  __shared__ alignas(16) unsigned short vt_s[2][64 * 68];  // V^T: row=d (68 u16)
  __shared__ float g_s[2][KB];

  const int tid = threadIdx.x;
  const int lane = tid & 63;
  const int wv = tid >> 6;
  const int hi = lane >> 5;
  const int l31 = lane & 31;
  const int vr2 = tid & 31;        // key-pair index (keys 2*vr2, 2*vr2+1)
  const int vc4 = tid >> 5;        // dim group (dims vc4*8 .. +7)
  const int bh = blockIdx.x;
  const int bb = bh / NHEAD;
  const int hh = bh % NHEAD;

  u32x4 kr[2], vr[2];
  float gr = 0.f;

#define A_ISSUE(T0, WG)                                                        \
  do {                                                                         \
    _Pragma("unroll") for (int i = 0; i < 2; ++i) {                            \
      const int idx = tid + (i << 8);                                          \
      const int r = idx >> 3, c = idx & 7;                                     \
      kr[i] = *(const u32x4*)&qkvb[(size_t)(bb * TT + (T0) + r) * 2304 +       \
                                   hh * 64 + 768 + c * 8];                     \
    }                                                                          \
    {                                                                          \
      const size_t vbase = (size_t)(bb * TT + (T0) + 2 * vr2) * 2304 +         \
                           hh * 64 + 1536 + vc4 * 8;                           \
      vr[0] = *(const u32x4*)&qkvb[vbase];                                     \
      vr[1] = *(const u32x4*)&qkvb[vbase + 2304];                              \
    }                                                                          \
    if (WG && tid < KB) gr = gate8[bb * TT + (T0) + tid];                      \
  } while (0)

#define A_WRITE(KD, VD, GD, WG)                                                \
  do {                                                                         \
    _Pragma("unroll") for (int i = 0; i < 2; ++i) {                            \
      const int idx = tid + (i << 8);                                          \
      const int r = idx >> 3, c = idx & 7;                                     \
      *(u32x4*)((char*)(KD) + r * 128 + ((c ^ (r & 7)) << 4)) = kr[i];         \
    }                                                                          \
    _Pragma("unroll") for (int k = 0; k < 8; ++k) {                            \
      const int j = k >> 1;                                                    \
      const u32 a0 = vr[0][j], a1 = vr[1][j];                                  \
      const u32 val = (k & 1) ? ((a0 >> 16) | (a1 & 0xffff0000u))              \
                              : ((a0 & 0xffffu) | (a1 << 16));                 \
      *(u32*)&(VD)[(vc4 * 8 + k) * 68 + 2 * vr2] = val;                        \
    }                                                                          \
    if (WG && tid < KB) (GD)[tid] = gr;                                        \
  } while (0)

#define QK_MFMA(KC)                                                            \
  do {                                                                         \
    _Pragma("unroll") for (int s = 0; s < 4; ++s) {                            \
      const int blk = (2 * s + hi) ^ (l31 & 7);                                \
      F4 f0, f1;                                                               \
      f0.u = *(const u32x4*)((const char*)(KC) + l31 * 128 + (blk << 4));      \
      f1.u = *(const u32x4*)((const char*)(KC) + (32 + l31) * 128 + (blk << 4));\
      S0 = __builtin_amdgcn_mfma_f32_32x32x16_bf16(f0.h, qf[s], S0, 0, 0, 0);  \
      S1 = __builtin_amdgcn_mfma_f32_32x32x16_bf16(f1.h, qf[s], S1, 0, 0, 0);  \
    }                                                                          \
  } while (0)

#define V_FRAGS(VC)                                                            \
  do {                                                                         \
    const char* vb0 = (const char*)(VC) + (size_t)l31 * 136 + hi * 8;          \
    const char* vb1 = vb0 + 32 * 136;                                          \
    _Pragma("unroll") for (int kb4 = 0; kb4 < 4; ++kb4) {                      \
      const u32x2 a0 = *(const u32x2*)(vb0 + 32 * kb4);                        \
      const u32x2 a1 = *(const u32x2*)(vb0 + 32 * kb4 + 16);                   \
      va[kb4].u = (u32x4){a0.x, a0.y, a1.x, a1.y};                             \
      const u32x2 c0 = *(const u32x2*)(vb1 + 32 * kb4);                        \
      const u32x2 c1 = *(const u32x2*)(vb1 + 32 * kb4 + 16);                   \
      vbf[kb4].u = (u32x4){c0.x, c0.y, c1.x, c1.y};                            \
    }                                                                          \
  } while (0)

// exp2-domain online softmax + PV with defer-rescale (THR=8).
#define SOFTMAX_PV(M, L, OA, OB)                                               \
  do {                                                                         \
    float red[8];                                                              \
    _Pragma("unroll") for (int i = 0; i < 8; ++i)                              \
      red[i] = fmaxf(fmaxf(S0[i], S0[i + 8]), fmaxf(S1[i], S1[i + 8]));        \
    _Pragma("unroll") for (int off = 4; off; off >>= 1)                        \
      _Pragma("unroll") for (int i = 0; i < off; ++i)                          \
        red[i] = fmaxf(red[i], red[i + off]);                                  \
    const float pmax = fmaxf(red[0], __shfl_xor(red[0], 32));                  \
    const int resc = __any(pmax > M + 8.f);                                    \
    float f = 1.f;                                                             \
    if (resc) {                                                                \
      const float mn = fmaxf(M, pmax);                                         \
      f = exp2f(M - mn);                                                       \
      M = mn;                                                                  \
    }                                                                          \
    _Pragma("unroll") for (int r = 0; r < 16; ++r) {                           \
      S0[r] = exp2f(S0[r] - M);                                                \
      S1[r] = exp2f(S1[r] - M);                                                \
    }                                                                          \
    _Pragma("unroll") for (int i = 0; i < 8; ++i)                              \
      red[i] = (S0[i] + S0[i + 8]) + (S1[i] + S1[i + 8]);                      \
    _Pragma("unroll") for (int off = 4; off; off >>= 1)                        \
      _Pragma("unroll") for (int i = 0; i < off; ++i)                          \
        red[i] += red[i + off];                                                \
    const float sum = red[0] + __shfl_xor(red[0], 32);                         \
    if (resc) {                                                                \
      L = L * f + sum;                                                         \
      _Pragma("unroll") for (int r = 0; r < 16; ++r) {                         \
        const float fq = __shfl(f, (r & 3) + 8 * (r >> 2) + 4 * hi);           \
        OA[r] *= fq;                                                           \
        OB[r] *= fq;                                                           \
      }                                                                        \
    } else {                                                                   \
      L += sum;                                                                \
    }                                                                          \
    u32 Pp[16];                                                                \
    _Pragma("unroll") for (int w = 0; w < 8; ++w) {                            \
      asm("v_cvt_pk_bf16_f32 %0, %1, %2" : "=v"(Pp[w]) : "v"(S0[2 * w]), "v"(S0[2 * w + 1])); \
      asm("v_cvt_pk_bf16_f32 %0, %1, %2" : "=v"(Pp[8 + w]) : "v"(S1[2 * w]), "v"(S1[2 * w + 1])); \
    }                                                                          \
    _Pragma("unroll") for (int kb4 = 0; kb4 < 4; ++kb4) {                      \
      F4 a;                                                                    \
      a.u = (u32x4){Pp[4 * kb4 + 0], Pp[4 * kb4 + 1], Pp[4 * kb4 + 2],         \
                    Pp[4 * kb4 + 3]};                                          \
      OA = __builtin_amdgcn_mfma_f32_32x32x16_bf16(a.h, va[kb4].h, OA, 0, 0, 0);\
      OB = __builtin_amdgcn_mfma_f32_32x32x16_bf16(a.h, vbf[kb4].h, OB, 0, 0, 0);\
    }                                                                          \
  } while (0)

  if (blockIdx.y >= 16) {
    // ================= stream 2: causal, gate-modulated, 4-tile chunks =====
    const int slot = (NSLOT - 1) - (blockIdx.y - 16);   // heavy slots first
    const int g = (slot < 2) ? 0 : (slot < 6) ? 1 : (slot < 12) ? 2 :
                  (slot < 20) ? 3 : (slot < 30) ? 4 : (slot < 42) ? 5 :
                  (slot < 56) ? 6 : 7;
    const int idxg = slot - g * (g + 1);
    const int e = (idxg >= g + 1) ? 1 : 0;
    const int qt = 2 * g + e;
    const int ch = idxg - e * (g + 1);
    const int r0 = qt * QBA;
    const int r0w = r0 + wv * 32;
    const int iq = r0w + l31;
    const int tlo = ch * 4;
    const int thi = min(tlo + 4, 2 * (qt + 1));

    bf16x8 qf[4];
    {
      const size_t qrow = (size_t)(bb * TT + r0w + l31) * 2304 + hh * 64;
#pragma unroll
      for (int s = 0; s < 4; ++s) {
        F4 f;
        f.u = *(const u32x4*)&qkvb[qrow + 16 * s + 8 * hi];
        qf[s] = f.h;
      }
    }

    float m2 = -1e30f, l2 = 0.f;
    f32x16 O2a, O2b;
#pragma unroll
    for (int r = 0; r < 16; ++r) { O2a[r] = 0.f; O2b[r] = 0.f; }

    A_ISSUE(tlo * 64, 1);
    A_WRITE(k_s[0], vt_s[0], g_s[0], 1);
    __syncthreads();

    int cur = 0;
    for (int t = tlo; t < thi; ++t) {
      const int t0 = t << 6;
      if (t + 1 < thi) A_ISSUE((t + 1) * 64, 1);
      if (t0 <= r0w + 31) {
        f32x16 S0, S1;
#pragma unroll
        for (int r = 0; r < 16; ++r) { S0[r] = 0.f; S1[r] = 0.f; }
        QK_MFMA(k_s[cur]);
        F4 va[4], vbf[4];
        V_FRAGS(vt_s[cur]);
        if (t0 + 63 <= r0w) {
          // interior: fully causal-valid for every lane of this wave
#pragma unroll
          for (int r = 0; r < 16; ++r) {
            const int crow = (r & 3) + 8 * (r >> 2) + 4 * hi;
            S0[r] *= g_s[cur][crow];
            S1[r] *= g_s[cur][32 + crow];
          }
        } else {
#pragma unroll
          for (int r = 0; r < 16; ++r) {
            const int crow = (r & 3) + 8 * (r >> 2) + 4 * hi;
            const int k0 = t0 + crow;
            S0[r] = (k0 <= iq) ? S0[r] * g_s[cur][crow] : -1e30f;
            S1[r] = (k0 + 32 <= iq) ? S1[r] * g_s[cur][32 + crow] : -1e30f;
          }
        }
        SOFTMAX_PV(m2, l2, O2a, O2b);
      }
      if (t + 1 < thi) A_WRITE(k_s[cur ^ 1], vt_s[cur ^ 1], g_s[cur ^ 1], 1);
      __syncthreads();
      cur ^= 1;
    }

    const size_t srow = ((size_t)bh * NSLOT + slot) * 128 + wv * 32;
    if (hi == 0) {
      float2 ml;
      ml.x = m2;
      ml.y = l2;
      *(float2*)&part2ML[(srow + l31) * 2] = ml;
    }
#pragma unroll
    for (int r = 0; r < 16; ++r) {
      const int crow = (r & 3) + 8 * (r >> 2) + 4 * hi;
      const size_t rowi = srow + crow;
      part2O[rowi * 64 + l31]      = b16(O2a[r]);
      part2O[rowi * 64 + 32 + l31] = b16(O2b[r]);
    }
  } else {
    // ================= stream 1: local window, raw scores (launched first) =
    const int qt = blockIdx.y;                   // 0..15
    const int r0 = qt * QBA;
    const int r0w = r0 + wv * 32;
    const int iq = r0w + l31;
    int tlo = (r0 - LWIN) >> 6;
    tlo = tlo < 0 ? 0 : tlo;
    const int thi = (r0 + QBA) >> 6;

    bf16x8 qf[4];
    {
      const size_t qrow = (size_t)(bb * TT + r0w + l31) * 2304 + hh * 64;
#pragma unroll
      for (int s = 0; s < 4; ++s) {
        F4 f;
        f.u = *(const u32x4*)&qkvb[qrow + 16 * s + 8 * hi];
        qf[s] = f.h;
      }
    }

    float m1 = -1e30f, l1 = 0.f;
    f32x16 O1a, O1b;
#pragma unroll
    for (int r = 0; r < 16; ++r) { O1a[r] = 0.f; O1b[r] = 0.f; }

    A_ISSUE(tlo * 64, 0);
    A_WRITE(k_s[0], vt_s[0], g_s[0], 0);
    __syncthreads();

    int cur = 0;
    for (int t = tlo; t < thi; ++t) {
      const int t0 = t << 6;
      if (t + 1 < thi) A_ISSUE((t + 1) * 64, 0);
      if (t0 + 63 >= r0w - LWIN && t0 <= r0w + 31) {
        f32x16 S0, S1;
#pragma unroll
        for (int r = 0; r < 16; ++r) { S0[r] = 0.f; S1[r] = 0.f; }
        QK_MFMA(k_s[cur]);
        F4 va[4], vbf[4];
        V_FRAGS(vt_s[cur]);
        if (t0 + 63 <= r0w && t0 >= r0w + 31 - LWIN) {
          // interior: every (row, key) of this wave inside the window
#pragma unroll
          for (int r = 0; r < 16; ++r) {
            S0[r] *= (0.125f * L2E);
            S1[r] *= (0.125f * L2E);
          }
        } else {
#pragma unroll
          for (int r = 0; r < 16; ++r) {
            const int crow = (r & 3) + 8 * (r >> 2) + 4 * hi;
            const int k0 = t0 + crow;
            const bool ok0 = (k0 <= iq) && (k0 + LWIN >= iq);
            const bool ok1 = (k0 + 32 <= iq) && (k0 + 32 + LWIN >= iq);
            S0[r] = ok0 ? S0[r] * (0.125f * L2E) : -1e30f;
            S1[r] = ok1 ? S1[r] * (0.125f * L2E) : -1e30f;
          }
        }
        SOFTMAX_PV(m1, l1, O1a, O1b);
      }
      if (t + 1 < thi) A_WRITE(k_s[cur ^ 1], vt_s[cur ^ 1], g_s[cur ^ 1], 0);
      __syncthreads();
      cur ^= 1;
    }

    const size_t obase = (((size_t)bh * 16 + qt) * 128 + wv * 32) * 64;
#pragma unroll
    for (int r = 0; r < 16; ++r) {
      const int crow = (r & 3) + 8 * (r >> 2) + 4 * hi;
      const float inv = 1.f / __shfl(l1, crow);
      part1O[obase + (size_t)crow * 64 + l31]      = b16(O1a[r] * inv);
      part1O[obase + (size_t)crow * 64 + 32 + l31] = b16(O1b[r] * inv);
    }
  }
#undef A_ISSUE
#undef A_WRITE
#undef QK_MFMA
#undef V_FRAGS
#undef SOFTMAX_PV
}

// ---------------------------------------------------------------- combine partials
// one thread = (bh, qrow, 8-d group): u32x4 coalesced IO, ml loaded once per chunk.
__global__ __launch_bounds__(256) void combine_kernel(
    const unsigned short* __restrict__ part1O,
    const unsigned short* __restrict__ part2O,
    const float* __restrict__ part2ML,
    const float* __restrict__ lwp, const float* __restrict__ gwp,
    unsigned short* __restrict__ aob) {
  const int t = blockIdx.x * 256 + threadIdx.x;   // [0, 24*2048*8)
  const int d8 = t & 7;
  const int rr = t >> 3;
  const int bh = rr >> 11;
  const int qrow = rr & 2047;
  const int qt = qrow >> 7, row = qrow & 127;
  const int g = qt >> 1;
  const int sb = g * (g + 1) + (qt & 1) * (g + 1);
  const int nc = g + 1;

  float m = -1e30f, l = 0.f;
  float oa[4], ob[4];
#pragma unroll
  for (int j = 0; j < 4; ++j) { oa[j] = 0.f; ob[j] = 0.f; }

  for (int c = 0; c < nc; ++c) {
    const size_t rowi = ((size_t)bh * NSLOT + sb + c) * 128 + row;
    const float2 ml = *(const float2*)&part2ML[rowi * 2];
    const u32x4 po = *(const u32x4*)&part2O[(rowi << 6) + 8 * d8];
    const float mn = fmaxf(m, ml.x);
    const float e0 = exp2f(m - mn), e1 = exp2f(ml.x - mn);
    l = l * e0 + ml.y * e1;
#pragma unroll
    for (int j = 0; j < 4; ++j) {
      oa[j] = oa[j] * e0 + __uint_as_float(po[j] << 16) * e1;
      ob[j] = ob[j] * e0 + __uint_as_float(po[j] & 0xffff0000u) * e1;
    }
    m = mn;
  }
  const u32x4 o1p = *(const u32x4*)&part1O[((((size_t)bh * 16 + qt) * 128 + row) << 6) + 8 * d8];
  const float wlr = 1.f / (1.f + __expf(-lwp[0]));
  const float wgr = 1.f / (1.f + __expf(-gwp[0]));
  const float wl = wlr / (wlr + wgr);
  const float wg = wgr / (wlr + wgr);
  const float s2 = wg / l;
  u32x4 outw;
#pragma unroll
  for (int j = 0; j < 4; ++j) {
    const float outa = wl * __uint_as_float(o1p[j] << 16) + oa[j] * s2;
    const float outb = wl * __uint_as_float(o1p[j] & 0xffff0000u) + ob[j] * s2;
    outw[j] = pk2(outa, outb);
  }
  const int bb = bh / NHEAD, hh = bh % NHEAD;
  *(u32x4*)&aob[(size_t)(bb * TT + qrow) * CC + hh * 64 + 8 * d8] = outw;
}

// ---------------------------------------------------------------- launch
extern "C" void kernel_launch(void* const* d_in, const int* in_sizes, int n_in,
                              void* d_out, int out_size, void* d_ws, size_t ws_size,
                              hipStream_t stream) {
  const float* x      = (const float*)d_in[0];
  const float* w_attn = (const float*)d_in[1];
  const float* b_attn = (const float*)d_in[2];
  const float* w_proj = (const float*)d_in[3];
  const float* b_proj = (const float*)d_in[4];
  const float* w_sel1 = (const float*)d_in[5];
  const float* b_sel1 = (const float*)d_in[6];
  const float* w_sel2 = (const float*)d_in[7];
  const float* b_sel2 = (const float*)d_in[8];
  const float* lw     = (const float*)d_in[9];
  const float* gw     = (const float*)d_in[10];
  float* out = (float*)d_out;

  // workspace carve
  unsigned short* qkvb  = (unsigned short*)d_ws;                 // 4096*2304 u16
  unsigned short* xb    = qkvb + (size_t)MROWS * 2304;           // 4096*768
  unsigned short* wtm   = xb + (size_t)MROWS * 768;              // 2560*768 (attn|sel1|pad)
  unsigned short* wtp   = wtm + (size_t)2560 * 768;              // 768*768
  unsigned short* aob   = wtp + (size_t)768 * 768;               // 4096*768
  unsigned short* part1O = aob + (size_t)MROWS * 768;            // 24*16*128*64
  unsigned short* part2O = part1O + (size_t)24 * 16 * 128 * 64;  // 24*72*128*64
  float* gatebuf = (float*)(part2O + (size_t)24 * NSLOT * 128 * 64);  // 4096 f32
  float* part2ML = gatebuf + MROWS;                              // 24*72*128*2 f32
  float* ghbuf   = part2ML + (size_t)24 * NSLOT * 128 * 2;       // 4096*192 f32

  prep_kernel<<<3984, 256, 0, stream>>>(x, xb, w_attn, wtm, w_proj, wtp, w_sel1);
  qkvsel_gemm_kernel<<<dim3(2560 / 128, MROWS / 128), 256, 0, stream>>>(
      xb, wtm, b_attn, b_sel1, qkvb, ghbuf, 768);
  gate_kernel<<<MROWS / 4, 256, 0, stream>>>(ghbuf, w_sel2, b_sel2, gatebuf);
  attn_part_kernel<<<dim3(BBATCH * NHEAD, NSLOT + 16), 256, 0, stream>>>(
      qkvb, gatebuf, part1O, part2O, part2ML);
  combine_kernel<<<(BBATCH * NHEAD * TT * 8) / 256, 256, 0, stream>>>(
      part1O, part2O, part2ML, lw, gw, aob);
  gemm_mfma_kernel<2, false, 0><<<dim3(768 / 64, MROWS / 128), 256, 0, stream>>>(
      aob, wtp, b_proj, out, MROWS, 768, 768);
}